// Round 3
// baseline (1658.844 us; speedup 1.0000x reference)
//
#include <hip/hip_runtime.h>
#include <math.h>

#define NSTEPS 3000
#define NWALK 1048576
#define BLOCK 256

// Threefry-2x32, 20 rounds, exactly JAX's schedule.
__device__ __forceinline__ void tf2x32(uint32_t k0, uint32_t k1,
                                       uint32_t x0, uint32_t x1,
                                       uint32_t& o0, uint32_t& o1) {
  uint32_t ks2 = k0 ^ k1 ^ 0x1BD11BDAu;
  x0 += k0; x1 += k1;
#define TFR(r) { x0 += x1; x1 = (x1 << r) | (x1 >> (32 - r)); x1 ^= x0; }
  TFR(13) TFR(15) TFR(26) TFR(6)
  x0 += k1;  x1 += ks2 + 1u;
  TFR(17) TFR(29) TFR(16) TFR(24)
  x0 += ks2; x1 += k0 + 2u;
  TFR(13) TFR(15) TFR(26) TFR(6)
  x0 += k0;  x1 += k1 + 3u;
  TFR(17) TFR(29) TFR(16) TFR(24)
  x0 += k1;  x1 += ks2 + 4u;
  TFR(13) TFR(15) TFR(26) TFR(6)
  x0 += ks2; x1 += k0 + 5u;
#undef TFR
  o0 = x0; o1 = x1;
}

// XLA CPU's log.f32: the Cephes/Eigen-3.3 plog polynomial that
// RewriteIRRuntimeFunctions/polynomial_approximations substitutes for
// llvm.log.f32. Strict f32 mul/add (VectorSupportLibrary::MulAdd is
// fmul+fadd, NO fma). Valid for positive normal inputs (our s is in
// [1.19e-7, 1.0000001], so edge masks are unnecessary).
__device__ __forceinline__ float xla_cpu_log_f32(float s) {
  uint32_t bits = __float_as_uint(s);
  int emm0 = (int)(bits >> 23) - 0x7f;
  float e = __fadd_rn((float)emm0, 1.0f);                 // exact
  float m = __uint_as_float((bits & 0x007fffffu) | 0x3f000000u);  // [0.5,1)
  bool mlt = m < 0.70710677f;        // f32(0.707106781186547524)
  float tmp = mlt ? m : 0.0f;
  float x = __fsub_rn(m, 1.0f);      // exact
  e = __fsub_rn(e, mlt ? 1.0f : 0.0f);
  x = __fadd_rn(x, tmp);             // (m-1)+m when mlt — exact
  float x2 = __fmul_rn(x, x);
  float x3 = __fmul_rn(x2, x);
  float y, y1, y2;
  y  = __fadd_rn(__fmul_rn(7.0376836292e-2f,  x), -1.1514610310e-1f);
  y1 = __fadd_rn(__fmul_rn(-1.2420140846e-1f, x),  1.4249322787e-1f);
  y2 = __fadd_rn(__fmul_rn(2.0000714765e-1f,  x), -2.4999993993e-1f);
  y  = __fadd_rn(__fmul_rn(y,  x),  1.1676998740e-1f);
  y1 = __fadd_rn(__fmul_rn(y1, x), -1.6668057665e-1f);
  y2 = __fadd_rn(__fmul_rn(y2, x),  3.3333331174e-1f);
  y  = __fadd_rn(__fmul_rn(y, x3), y1);
  y  = __fadd_rn(__fmul_rn(y, x3), y2);
  y  = __fmul_rn(y, x3);
  y1 = __fmul_rn(e, -2.12194440e-4f);   // cephes_log_q1
  tmp = __fmul_rn(x2, 0.5f);
  y  = __fadd_rn(y, y1);
  x  = __fsub_rn(x, tmp);
  y2 = __fmul_rn(e, 0.693359375f);      // cephes_log_q2
  x  = __fadd_rn(x, y);
  x  = __fadd_rn(x, y2);
  return x;
}

// XLA ElementalIrEmitter::EmitErfInv, f32 path (Giles):
//   w = -log((1-x)*(1+x));  branch at w<5;  Horner p = p*w' + c.
__device__ __forceinline__ float xla_erfinv_f32(float x) {
  float s = __fmul_rn(__fsub_rn(1.0f, x), __fadd_rn(1.0f, x));
  float w = -xla_cpu_log_f32(s);
  float p;
  if (w < 5.0f) {
    float v = __fsub_rn(w, 2.5f);
    p = 2.81022636e-08f;
    p = __fadd_rn(__fmul_rn(p, v), 3.43273939e-07f);
    p = __fadd_rn(__fmul_rn(p, v), -3.5233877e-06f);
    p = __fadd_rn(__fmul_rn(p, v), -4.39150654e-06f);
    p = __fadd_rn(__fmul_rn(p, v), 0.00021858087f);
    p = __fadd_rn(__fmul_rn(p, v), -0.00125372503f);
    p = __fadd_rn(__fmul_rn(p, v), -0.00417768164f);
    p = __fadd_rn(__fmul_rn(p, v), 0.246640727f);
    p = __fadd_rn(__fmul_rn(p, v), 1.50140941f);
  } else {
    float v = __fsub_rn(__fsqrt_rn(w), 3.0f);
    p = -0.000200214257f;
    p = __fadd_rn(__fmul_rn(p, v), 0.000100950558f);
    p = __fadd_rn(__fmul_rn(p, v), 0.00134934322f);
    p = __fadd_rn(__fmul_rn(p, v), -0.00367342844f);
    p = __fadd_rn(__fmul_rn(p, v), 0.00573950773f);
    p = __fadd_rn(__fmul_rn(p, v), -0.0076224613f);
    p = __fadd_rn(__fmul_rn(p, v), 0.00943887047f);
    p = __fadd_rn(__fmul_rn(p, v), 1.00167406f);
    p = __fadd_rn(__fmul_rn(p, v), 2.83297682f);
  }
  return __fmul_rn(p, x);
}

// jax.random.normal f32: u = uniform(nextafter(-1,0), 1); z = sqrt(2)*erfinv(u)
__device__ __forceinline__ float normal_from_bits(uint32_t bits) {
  const float MINVAL = __uint_as_float(0xBF7FFFFFu);   // -0.99999994 = nextafter(-1,0)
  float f = __uint_as_float((bits >> 9) | 0x3F800000u) - 1.0f;  // exact in [0,1)
  // (maxval-minval) constant-folds to exactly 2.0f (tie-to-even)
  float u = __fadd_rn(__fmul_rn(f, 2.0f), MINVAL);
  u = fmaxf(MINVAL, u);
  const float SQRT2 = __uint_as_float(0x3FB504F3u);    // float(sqrt(2))
  return __fmul_rn(SQRT2, xla_erfinv_f32(u));
}

__global__ __launch_bounds__(BLOCK)
void ddm_kernel(const float* __restrict__ sv_p, const float* __restrict__ rate_p,
                const float* __restrict__ ndt_p, const float* __restrict__ thr_p,
                const float* __restrict__ noise_p, const float* __restrict__ dt_p,
                const int* __restrict__ nw_p, float* __restrict__ out) {
  // Per-step keys: jax.random.split(key(0), 3000) (threefry_partitionable
  // foldlike): keys[t] = (o0,o1) of cipher((0,0), (0,t)). Cached in LDS.
  __shared__ uint2 skeys[NSTEPS];
  int tid = threadIdx.x;
  for (int t = tid; t < NSTEPS; t += BLOCK) {
    uint32_t a, b;
    tf2x32(0u, 0u, 0u, (uint32_t)t, a, b);
    skeys[t] = make_uint2(a, b);
  }
  __syncthreads();

  int i = blockIdx.x * BLOCK + tid;
  int nw = *nw_p;
  if (i >= nw) return;

  float sv = *sv_p, rate = *rate_p, ndt = *ndt_p, thr = *thr_p,
        noise = *noise_p, dt = *dt_p;
  float rate_dt = __fmul_rn(rate, dt);
  float sqrt_dt = __fsqrt_rn(dt);

  float p = __fadd_rn(0.0f, sv);  // zeros + starting_value
  float rts = 0.0f;
  uint32_t ui = (uint32_t)i;

  // Frozen-after-crossing => per-lane early exit is exact, not approximate.
#pragma unroll 1
  for (int t = 0; t < NSTEPS; ++t) {
    rts = __fadd_rn(rts, 1.0f);
    uint2 k = skeys[t];
    uint32_t b1, b2;
    // _threefry_random_bits_partitionable, bit_width=32:
    //   bits1, bits2 = cipher(key_t, (hi=0, lo=i));  bits = bits1 ^ bits2
    tf2x32(k.x, k.y, 0u, ui, b1, b2);
    float z = normal_from_bits(b1 ^ b2);
    float dw = __fadd_rn(rate_dt, __fmul_rn(noise, z));   // (rate*dt + noise*z)*1
    p = __fadd_rn(p, __fmul_rn(dw, sqrt_dt));
    if (!(fabsf(p) < thr)) break;   // active = |particle| < threshold
  }

  out[i] = __fadd_rn(ndt, __fmul_rn(rts, dt));
  out[nw + i] = (p <= -thr) ? 0.0f : 1.0f;
}

extern "C" void kernel_launch(void* const* d_in, const int* in_sizes, int n_in,
                              void* d_out, int out_size, void* d_ws, size_t ws_size,
                              hipStream_t stream) {
  const float* sv    = (const float*)d_in[0];
  const float* rate  = (const float*)d_in[1];
  const float* ndt   = (const float*)d_in[2];
  const float* thr   = (const float*)d_in[3];
  const float* noise = (const float*)d_in[4];
  const float* dt    = (const float*)d_in[5];
  const int*   nw    = (const int*)d_in[6];
  float* out = (float*)d_out;

  int nblocks = (NWALK + BLOCK - 1) / BLOCK;  // num_walkers fixed at 1048576 by setup
  ddm_kernel<<<nblocks, BLOCK, 0, stream>>>(sv, rate, ndt, thr, noise, dt, nw, out);
}